// Round 8
// baseline (590.698 us; speedup 1.0000x reference)
//
#include <hip/hip_runtime.h>
#include <cstdint>

#define LEAKY 0.2f
#define LN_EPS 1e-5f

typedef __attribute__((ext_vector_type(8))) short short8;   // 8 x bf16 (4 VGPR)
typedef __attribute__((ext_vector_type(4))) float f32x4;    // MFMA accum
typedef __attribute__((ext_vector_type(2))) float f32x2;    // NT-compatible float2

__device__ __forceinline__ ushort bf16_rne(float x) {
    unsigned u = __float_as_uint(x);
    unsigned r = (u + 0x7fffu + ((u >> 16) & 1u)) >> 16;
    return (ushort)r;
}
__device__ __forceinline__ float bf16_to_f(ushort h) {
    return __uint_as_float(((unsigned)h) << 16);
}

// ---------------------------------------------------------------------------
// CSR build: histogram, hierarchical exclusive scan, scatter
// ---------------------------------------------------------------------------
__global__ void hist_kernel(const int* __restrict__ ei, int er, int etot,
                            int* __restrict__ deg) {
    int e = blockIdx.x * blockDim.x + threadIdx.x;
    if (e >= etot) return;
    int dst = (e < er) ? ei[er + e] : (e - er);   // self-loops appended
    atomicAdd(&deg[dst], 1);
}

__global__ __launch_bounds__(1024) void scanA(const int* __restrict__ deg,
                                              int* __restrict__ escan,
                                              int* __restrict__ bsum, int n) {
    __shared__ int wsum[16], wpre[16];
    const int lane = threadIdx.x & 63, wv = threadIdx.x >> 6;
    const int i = blockIdx.x * 1024 + threadIdx.x;
    int v = (i < n) ? deg[i] : 0;
    int x = v;
#pragma unroll
    for (int off = 1; off < 64; off <<= 1) {
        int y = __shfl_up(x, off, 64);
        if (lane >= off) x += y;
    }
    if (lane == 63) wsum[wv] = x;
    __syncthreads();
    if (wv == 0) {
        int s = (lane < 16) ? wsum[lane] : 0;
#pragma unroll
        for (int off = 1; off < 16; off <<= 1) {
            int y = __shfl_up(s, off, 64);
            if (lane >= off) s += y;
        }
        if (lane < 16) wpre[lane] = s;
    }
    __syncthreads();
    int excl = x - v + (wv ? wpre[wv - 1] : 0);
    if (i < n) escan[i] = excl;
    if (threadIdx.x == 1023) bsum[blockIdx.x] = wpre[15];
}

__global__ __launch_bounds__(1024) void scanB(const int* __restrict__ bsum,
                                              int* __restrict__ bpre, int nb,
                                              int* __restrict__ offs, int n) {
    __shared__ int wsum[16], wpre[16];
    const int lane = threadIdx.x & 63, wv = threadIdx.x >> 6;
    const int i = threadIdx.x;
    int v = (i < nb) ? bsum[i] : 0;
    int x = v;
#pragma unroll
    for (int off = 1; off < 64; off <<= 1) {
        int y = __shfl_up(x, off, 64);
        if (lane >= off) x += y;
    }
    if (lane == 63) wsum[wv] = x;
    __syncthreads();
    if (wv == 0) {
        int s = (lane < 16) ? wsum[lane] : 0;
#pragma unroll
        for (int off = 1; off < 16; off <<= 1) {
            int y = __shfl_up(s, off, 64);
            if (lane >= off) s += y;
        }
        if (lane < 16) wpre[lane] = s;
    }
    __syncthreads();
    if (i < nb) bpre[i] = x - v + (wv ? wpre[wv - 1] : 0);
    if (threadIdx.x == 1023) offs[n] = wpre[15];
}

__global__ void scanC(const int* __restrict__ escan, const int* __restrict__ bpre,
                      int* __restrict__ offs, int* __restrict__ woff, int n) {
    int i = blockIdx.x * 256 + threadIdx.x;
    if (i >= n) return;
    int o = escan[i] + bpre[i >> 10];
    offs[i] = o;
    woff[i] = o;
}

__global__ void fill_kernel(const int* __restrict__ ei, int er, int etot,
                            int* __restrict__ woff, int* __restrict__ colv) {
    int e = blockIdx.x * blockDim.x + threadIdx.x;
    if (e >= etot) return;
    int src, dst;
    if (e < er) { src = ei[e]; dst = ei[er + e]; }
    else        { src = dst = e - er; }
    int pos = atomicAdd(&woff[dst], 1);
    colv[pos] = src;
}

// ---------------------------------------------------------------------------
// W -> per-MFMA-fragment bf16 hi/lo layout so gemm B-loads are coalesced.
// Wf[colblk(16)][ks(4)][lane(64)][j(8)]: value W[k][col],
//   col = colblk*16 + (lane&15), k = ks*32 + (lane>>4)*8 + j.
// colblk 0..7 = Wl cols, 8..15 = Wr cols.
// ---------------------------------------------------------------------------
__global__ void cvt_w(const float* __restrict__ Wl, const float* __restrict__ Wr,
                      ushort* __restrict__ Whi, ushort* __restrict__ Wlo) {
    int t = blockIdx.x * 256 + threadIdx.x;     // 0..32767
    int colblk = t >> 11;
    int ks = (t >> 9) & 3;
    int lane = (t >> 3) & 63;
    int j = t & 7;
    int col = colblk * 16 + (lane & 15);
    int k = ks * 32 + (lane >> 4) * 8 + j;
    float v = (col < 128) ? Wl[(size_t)k * 128 + col]
                          : Wr[(size_t)k * 128 + (col - 128)];
    ushort h = bf16_rne(v);
    Whi[t] = h;
    Wlo[t] = bf16_rne(v - bf16_to_f(h));
}

// ---------------------------------------------------------------------------
// Dual GEMM via split-bf16 MFMA. Block = 4 waves, 64-row tile.
// ks-loop NOT unrolled + B loads inside nt-loop: round-6 full unroll hoisted
// 16 B-frag loads (128 VGPR) -> likely spill. Live set now ~acc64+A32+B8.
// A split: hi = truncate (1 op), lo = rne(x - hi): pair still ~2^-16 exact.
// ---------------------------------------------------------------------------
__global__ __launch_bounds__(256) void gemm_mfma(
    const float* __restrict__ X,
    const ushort* __restrict__ Wfhi, const ushort* __restrict__ Wflo,
    float* __restrict__ Ol, float* __restrict__ Or, int nrows) {
    __shared__ float xs[64 * 32 * 4];           // 32 KiB, float4 slot = row*32 + (kc^(row&7))
    const int t = threadIdx.x;
    const int wave = t >> 6, lane = t & 63;
    const int m0 = blockIdx.x * 64;
    {   // stage X tile: 2048 float4, 8 per thread, coalesced
        const float4* Xv = (const float4*)X + (size_t)m0 * 32;
        float4* xsv = (float4*)xs;
#pragma unroll
        for (int i = 0; i < 8; ++i) {
            int idx = i * 256 + t;
            int row = idx >> 5, kc = idx & 31;
            float4 v = {0.f, 0.f, 0.f, 0.f};
            if (m0 + row < nrows) v = Xv[idx];
            xsv[row * 32 + (kc ^ (row & 7))] = v;
        }
    }
    __syncthreads();

    const int lrow = lane & 15;
    const int lkc = (lane >> 4) * 2;            // 16B-slot offset within ks block
    f32x4 acc[4][4];
#pragma unroll
    for (int mt = 0; mt < 4; ++mt)
#pragma unroll
        for (int nt = 0; nt < 4; ++nt) acc[mt][nt] = (f32x4){0.f, 0.f, 0.f, 0.f};

#pragma unroll 1
    for (int ks = 0; ks < 4; ++ks) {
        short8 ahi[4], alo[4];
#pragma unroll
        for (int mt = 0; mt < 4; ++mt) {
            const int row = mt * 16 + lrow;
            const int kc0 = ks * 8 + lkc;
            float4 v0 = ((const float4*)xs)[row * 32 + (kc0 ^ (row & 7))];
            float4 v1 = ((const float4*)xs)[row * 32 + ((kc0 + 1) ^ (row & 7))];
            float e[8];
            e[0] = v0.x; e[1] = v0.y; e[2] = v0.z; e[3] = v0.w;
            e[4] = v1.x; e[5] = v1.y; e[6] = v1.z; e[7] = v1.w;
#pragma unroll
            for (int j = 0; j < 8; ++j) {
                ushort h = (ushort)(__float_as_uint(e[j]) >> 16);   // truncate split
                ahi[mt][j] = (short)h;
                alo[mt][j] = (short)bf16_rne(e[j] - bf16_to_f(h));
            }
        }
#pragma unroll
        for (int nt = 0; nt < 4; ++nt) {
            size_t off = (((size_t)(wave * 4 + nt) * 4 + ks) * 64 + lane) * 8;
            short8 bhi = *(const short8*)&Wfhi[off];
            short8 blo = *(const short8*)&Wflo[off];
#pragma unroll
            for (int mt = 0; mt < 4; ++mt) {
                acc[mt][nt] = __builtin_amdgcn_mfma_f32_16x16x32_bf16(
                    alo[mt], bhi, acc[mt][nt], 0, 0, 0);
                acc[mt][nt] = __builtin_amdgcn_mfma_f32_16x16x32_bf16(
                    ahi[mt], blo, acc[mt][nt], 0, 0, 0);
                acc[mt][nt] = __builtin_amdgcn_mfma_f32_16x16x32_bf16(
                    ahi[mt], bhi, acc[mt][nt], 0, 0, 0);
            }
        }
    }
    // Epilogue. C/D frag: col = lane&15, row = (lane>>4)*4 + i  [m89 layout].
    float* __restrict__ O = (wave < 2) ? Ol : Or;
    const int cbase = (wave * 64) & 127;
    const int crow0 = (lane >> 4) * 4;
#pragma unroll
    for (int mt = 0; mt < 4; ++mt) {
#pragma unroll
        for (int i = 0; i < 4; ++i) {
            const int row = m0 + mt * 16 + crow0 + i;
            if (row >= nrows) continue;
#pragma unroll
            for (int nt = 0; nt < 4; ++nt) {
                const int col = cbase + nt * 16 + lrow;
                O[(size_t)row * 128 + col] = acc[mt][nt][i];
            }
        }
    }
}

// ---------------------------------------------------------------------------
// Fused GATv2 aggregation + bias + ELU + residual + LayerNorm.
// One wave per destination node; static grid-stride. Streaming data (xr,
// resid, out) uses non-temporal hints so L3 retains the 51 MB xl gather array.
// ---------------------------------------------------------------------------
__global__ __launch_bounds__(256) void gat_agg(
    const float* __restrict__ xl, const float* __restrict__ xr,
    const int* __restrict__ offs, const int* __restrict__ colv,
    const float* __restrict__ att,
    const float* __restrict__ bias, const float* __restrict__ gamma,
    const float* __restrict__ beta, const float* __restrict__ resid,
    float* __restrict__ out, int nnode) {
    const int lane = threadIdx.x & 63;
    const int wave0 = blockIdx.x * 4 + (threadIdx.x >> 6);
    const int wstride = gridDim.x * 4;
    const f32x2* __restrict__ xlb = (const f32x2*)xl + lane;
    const f32x2 att2 = ((const f32x2*)att)[lane];
    const f32x2 b2 = ((const f32x2*)bias)[lane];
    const f32x2 g2 = ((const f32x2*)gamma)[lane];
    const f32x2 be2 = ((const f32x2*)beta)[lane];
    for (int gid = wave0; gid < nnode; gid += wstride) {
        const f32x2 xr2 = __builtin_nontemporal_load(
            (const f32x2*)xr + (size_t)gid * 64 + lane);
        float den = 0.f, acc0 = 0.f, acc1 = 0.f;
        int e = offs[gid];
        const int e1 = offs[gid + 1];
        for (; e + 4 <= e1; e += 4) {   // 4-edge unroll: MLP on the gather
            int s0 = colv[e], s1 = colv[e + 1], s2 = colv[e + 2], s3 = colv[e + 3];
            f32x2 a0 = xlb[(size_t)s0 * 64];
            f32x2 a1 = xlb[(size_t)s1 * 64];
            f32x2 a2 = xlb[(size_t)s2 * 64];
            f32x2 a3 = xlb[(size_t)s3 * 64];
            float m0x = a0.x + xr2.x, m0y = a0.y + xr2.y;
            float m1x = a1.x + xr2.x, m1y = a1.y + xr2.y;
            float m2x = a2.x + xr2.x, m2y = a2.y + xr2.y;
            float m3x = a3.x + xr2.x, m3y = a3.y + xr2.y;
            m0x = fmaxf(m0x, LEAKY * m0x); m0y = fmaxf(m0y, LEAKY * m0y);
            m1x = fmaxf(m1x, LEAKY * m1x); m1y = fmaxf(m1y, LEAKY * m1y);
            m2x = fmaxf(m2x, LEAKY * m2x); m2y = fmaxf(m2y, LEAKY * m2y);
            m3x = fmaxf(m3x, LEAKY * m3x); m3y = fmaxf(m3y, LEAKY * m3y);
            float p0 = m0x * att2.x + m0y * att2.y;
            float p1 = m1x * att2.x + m1y * att2.y;
            float p2 = m2x * att2.x + m2y * att2.y;
            float p3 = m3x * att2.x + m3y * att2.y;
            p0 += __shfl_xor(p0, 1); p0 += __shfl_xor(p0, 2); p0 += __shfl_xor(p0, 4);
            p1 += __shfl_xor(p1, 1); p1 += __shfl_xor(p1, 2); p1 += __shfl_xor(p1, 4);
            p2 += __shfl_xor(p2, 1); p2 += __shfl_xor(p2, 2); p2 += __shfl_xor(p2, 4);
            p3 += __shfl_xor(p3, 1); p3 += __shfl_xor(p3, 2); p3 += __shfl_xor(p3, 4);
            float ex0 = __expf(p0), ex1 = __expf(p1);
            float ex2 = __expf(p2), ex3 = __expf(p3);
            den += (ex0 + ex1) + (ex2 + ex3);
            acc0 += a0.x * ex0 + a1.x * ex1 + a2.x * ex2 + a3.x * ex3;
            acc1 += a0.y * ex0 + a1.y * ex1 + a2.y * ex2 + a3.y * ex3;
        }
        for (; e < e1; ++e) {
            int s0 = colv[e];
            f32x2 a0 = xlb[(size_t)s0 * 64];
            float m0x = a0.x + xr2.x, m0y = a0.y + xr2.y;
            m0x = fmaxf(m0x, LEAKY * m0x);
            m0y = fmaxf(m0y, LEAKY * m0y);
            float p0 = m0x * att2.x + m0y * att2.y;
            p0 += __shfl_xor(p0, 1); p0 += __shfl_xor(p0, 2); p0 += __shfl_xor(p0, 4);
            float ex0 = __expf(p0);
            den += ex0;
            acc0 += a0.x * ex0;
            acc1 += a0.y * ex0;
        }
        float inv_den = 1.f / den;
        float v0 = acc0 * inv_den + b2.x;
        float v1 = acc1 * inv_den + b2.y;
        v0 = v0 > 0.f ? v0 : expm1f(v0);     // ELU (alpha=1)
        v1 = v1 > 0.f ? v1 : expm1f(v1);
        const f32x2 r2 = __builtin_nontemporal_load(
            (const f32x2*)resid + (size_t)gid * 64 + lane);
        float t0 = v0 + r2.x, t1 = v1 + r2.y;
        float s = t0 + t1, ss = t0 * t0 + t1 * t1;
#pragma unroll
        for (int m = 1; m < 64; m <<= 1) {
            s += __shfl_xor(s, m);
            ss += __shfl_xor(ss, m);
        }
        const float mu = s * 0.0078125f;
        const float var = ss * 0.0078125f - mu * mu;
        const float iv = rsqrtf(var + LN_EPS);
        f32x2 o;
        o.x = (t0 - mu) * iv * g2.x + be2.x;
        o.y = (t1 - mu) * iv * g2.y + be2.y;
        __builtin_nontemporal_store(o, (f32x2*)out + (size_t)gid * 64 + lane);
    }
}

// ---------------------------------------------------------------------------
extern "C" void kernel_launch(void* const* d_in, const int* in_sizes, int n_in,
                              void* d_out, int out_size, void* d_ws, size_t ws_size,
                              hipStream_t stream) {
    const float* x   = (const float*)d_in[0];
    const int*   ei  = (const int*)d_in[1];
    const float* Wl0 = (const float*)d_in[2];
    const float* Wr0 = (const float*)d_in[3];
    const float* at0 = (const float*)d_in[4];
    const float* b0  = (const float*)d_in[5];
    const float* g0  = (const float*)d_in[6];
    const float* be0 = (const float*)d_in[7];
    const float* Wl1 = (const float*)d_in[8];
    const float* Wr1 = (const float*)d_in[9];
    const float* at1 = (const float*)d_in[10];
    const float* b1  = (const float*)d_in[11];
    const float* g1  = (const float*)d_in[12];
    const float* be1 = (const float*)d_in[13];

    const int NF = in_sizes[0];        // N*128
    const int n  = NF / 128;           // nodes
    const int er = in_sizes[1] / 2;    // raw edges
    const int etot = er + n;           // + self-loops
    const int nb = (n + 1023) / 1024;  // scan blocks

    float* A    = (float*)d_ws;        // xl  (N*128)
    float* B    = A + (size_t)NF;      // xr  (N*128)
    ushort* Whi = (ushort*)(B + (size_t)NF);   // 32768 bf16 hi (frag layout)
    ushort* Wlo = Whi + 32768;                 // 32768 bf16 lo
    int* deg    = (int*)(Wlo + 32768);
    int* woff   = deg + n;
    int* offs   = woff + n;
    int* escan  = offs + (n + 1);
    int* bsum   = escan + n;
    int* bpre   = bsum + 1024;
    int* colv   = bpre + 1024;
    float* C    = (float*)d_out;       // layer-1 output / residual / final out

    // ---- CSR build (shared by both layers) ----
    (void)hipMemsetAsync(deg, 0, (size_t)n * sizeof(int), stream);
    hist_kernel<<<(etot + 255) / 256, 256, 0, stream>>>(ei, er, etot, deg);
    scanA<<<nb, 1024, 0, stream>>>(deg, escan, bsum, n);
    scanB<<<1, 1024, 0, stream>>>(bsum, bpre, nb, offs, n);
    scanC<<<(n + 255) / 256, 256, 0, stream>>>(escan, bpre, offs, woff, n);
    fill_kernel<<<(etot + 255) / 256, 256, 0, stream>>>(ei, er, etot, woff, colv);

    const int gblk = (n + 63) / 64;

    // ---- layer 1 ----
    cvt_w<<<128, 256, 0, stream>>>(Wl0, Wr0, Whi, Wlo);
    gemm_mfma<<<gblk, 256, 0, stream>>>(x, Whi, Wlo, A, B, n);
    gat_agg<<<2048, 256, 0, stream>>>(A, B, offs, colv, at0, b0, g0, be0,
                                      x, C, n);
    // ---- layer 2 ----
    cvt_w<<<128, 256, 0, stream>>>(Wl1, Wr1, Whi, Wlo);
    gemm_mfma<<<gblk, 256, 0, stream>>>(C, Whi, Wlo, A, B, n);
    gat_agg<<<2048, 256, 0, stream>>>(A, B, offs, colv, at1, b1, g1, be1,
                                      C, C, n);
}

// Round 11
// 527.409 us; speedup vs baseline: 1.1200x; 1.1200x over previous
//
#include <hip/hip_runtime.h>
#include <cstdint>

#define LEAKY 0.2f
#define LN_EPS 1e-5f

typedef __attribute__((ext_vector_type(8))) short short8;   // 8 x bf16 (4 VGPR)
typedef __attribute__((ext_vector_type(4))) float f32x4;    // MFMA accum
typedef __attribute__((ext_vector_type(2))) float f32x2;    // NT-compatible float2

__device__ __forceinline__ ushort bf16_rne(float x) {
    unsigned u = __float_as_uint(x);
    unsigned r = (u + 0x7fffu + ((u >> 16) & 1u)) >> 16;
    return (ushort)r;
}
__device__ __forceinline__ float bf16_to_f(ushort h) {
    return __uint_as_float(((unsigned)h) << 16);
}

// ---------------------------------------------------------------------------
// CSR build: histogram, hierarchical exclusive scan, scatter
// ---------------------------------------------------------------------------
__global__ void hist_kernel(const int* __restrict__ ei, int er, int etot,
                            int* __restrict__ deg) {
    int e = blockIdx.x * blockDim.x + threadIdx.x;
    if (e >= etot) return;
    int dst = (e < er) ? ei[er + e] : (e - er);   // self-loops appended
    atomicAdd(&deg[dst], 1);
}

__global__ __launch_bounds__(1024) void scanA(const int* __restrict__ deg,
                                              int* __restrict__ escan,
                                              int* __restrict__ bsum, int n) {
    __shared__ int wsum[16], wpre[16];
    const int lane = threadIdx.x & 63, wv = threadIdx.x >> 6;
    const int i = blockIdx.x * 1024 + threadIdx.x;
    int v = (i < n) ? deg[i] : 0;
    int x = v;
#pragma unroll
    for (int off = 1; off < 64; off <<= 1) {
        int y = __shfl_up(x, off, 64);
        if (lane >= off) x += y;
    }
    if (lane == 63) wsum[wv] = x;
    __syncthreads();
    if (wv == 0) {
        int s = (lane < 16) ? wsum[lane] : 0;
#pragma unroll
        for (int off = 1; off < 16; off <<= 1) {
            int y = __shfl_up(s, off, 64);
            if (lane >= off) s += y;
        }
        if (lane < 16) wpre[lane] = s;
    }
    __syncthreads();
    int excl = x - v + (wv ? wpre[wv - 1] : 0);
    if (i < n) escan[i] = excl;
    if (threadIdx.x == 1023) bsum[blockIdx.x] = wpre[15];
}

__global__ __launch_bounds__(1024) void scanB(const int* __restrict__ bsum,
                                              int* __restrict__ bpre, int nb,
                                              int* __restrict__ offs, int n) {
    __shared__ int wsum[16], wpre[16];
    const int lane = threadIdx.x & 63, wv = threadIdx.x >> 6;
    const int i = threadIdx.x;
    int v = (i < nb) ? bsum[i] : 0;
    int x = v;
#pragma unroll
    for (int off = 1; off < 64; off <<= 1) {
        int y = __shfl_up(x, off, 64);
        if (lane >= off) x += y;
    }
    if (lane == 63) wsum[wv] = x;
    __syncthreads();
    if (wv == 0) {
        int s = (lane < 16) ? wsum[lane] : 0;
#pragma unroll
        for (int off = 1; off < 16; off <<= 1) {
            int y = __shfl_up(s, off, 64);
            if (lane >= off) s += y;
        }
        if (lane < 16) wpre[lane] = s;
    }
    __syncthreads();
    if (i < nb) bpre[i] = x - v + (wv ? wpre[wv - 1] : 0);
    if (threadIdx.x == 1023) offs[n] = wpre[15];
}

__global__ void scanC(const int* __restrict__ escan, const int* __restrict__ bpre,
                      int* __restrict__ offs, int* __restrict__ woff, int n) {
    int i = blockIdx.x * 256 + threadIdx.x;
    if (i >= n) return;
    int o = escan[i] + bpre[i >> 10];
    offs[i] = o;
    woff[i] = o;
}

__global__ void fill_kernel(const int* __restrict__ ei, int er, int etot,
                            int* __restrict__ woff, int* __restrict__ colv) {
    int e = blockIdx.x * blockDim.x + threadIdx.x;
    if (e >= etot) return;
    int src, dst;
    if (e < er) { src = ei[e]; dst = ei[er + e]; }
    else        { src = dst = e - er; }
    int pos = atomicAdd(&woff[dst], 1);
    colv[pos] = src;
}

// ---------------------------------------------------------------------------
// Both layers' W -> per-MFMA-fragment bf16 hi/lo layout (one dispatch).
// Wf[layer][colblk(16)][ks(4)][lane(64)][j(8)]: value W[k][col],
//   col = colblk*16 + (lane&15), k = ks*32 + (lane>>4)*8 + j.
// colblk 0..7 = Wl cols, 8..15 = Wr cols.
// ---------------------------------------------------------------------------
__global__ void cvt_w2(const float* __restrict__ Wl0, const float* __restrict__ Wr0,
                       const float* __restrict__ Wl1, const float* __restrict__ Wr1,
                       ushort* __restrict__ Whi, ushort* __restrict__ Wlo) {
    int t = blockIdx.x * 256 + threadIdx.x;     // 0..65535
    int layer = t >> 15;
    int i = t & 32767;
    int colblk = i >> 11;
    int ks = (i >> 9) & 3;
    int lane = (i >> 3) & 63;
    int j = i & 7;
    int col = colblk * 16 + (lane & 15);
    int k = ks * 32 + (lane >> 4) * 8 + j;
    const float* Wl = layer ? Wl1 : Wl0;
    const float* Wr = layer ? Wr1 : Wr0;
    float v = (col < 128) ? Wl[(size_t)k * 128 + col]
                          : Wr[(size_t)k * 128 + (col - 128)];
    ushort h = bf16_rne(v);
    Whi[t] = h;
    Wlo[t] = bf16_rne(v - bf16_to_f(h));
}

// ---------------------------------------------------------------------------
// Dual GEMM via split-bf16 MFMA. Block = 4 waves, 64-row tile.
// X tile staged in LDS (XOR-swizzled); B frags from pre-swizzled Wf (L2-hot).
// Output packed to bf16 pairs (uint) via shfl_xor lane-pairing: halves the
// write traffic AND halves gat_agg's gather working set (xl fits L3 easily).
// ---------------------------------------------------------------------------
__global__ __launch_bounds__(256) void gemm_mfma(
    const float* __restrict__ X,
    const ushort* __restrict__ Wfhi, const ushort* __restrict__ Wflo,
    uint* __restrict__ Olb, uint* __restrict__ Orb, int nrows) {
    __shared__ float xs[64 * 32 * 4];           // 32 KiB, float4 slot = row*32 + (kc^(row&7))
    const int t = threadIdx.x;
    const int wave = t >> 6, lane = t & 63;
    const int m0 = blockIdx.x * 64;
    {   // stage X tile: 2048 float4, 8 per thread, coalesced
        const float4* Xv = (const float4*)X + (size_t)m0 * 32;
        float4* xsv = (float4*)xs;
#pragma unroll
        for (int i = 0; i < 8; ++i) {
            int idx = i * 256 + t;
            int row = idx >> 5, kc = idx & 31;
            float4 v = {0.f, 0.f, 0.f, 0.f};
            if (m0 + row < nrows) v = Xv[idx];
            xsv[row * 32 + (kc ^ (row & 7))] = v;
        }
    }
    __syncthreads();

    const int lrow = lane & 15;
    const int lkc = (lane >> 4) * 2;            // 16B-slot offset within ks block
    f32x4 acc[4][4];
#pragma unroll
    for (int mt = 0; mt < 4; ++mt)
#pragma unroll
        for (int nt = 0; nt < 4; ++nt) acc[mt][nt] = (f32x4){0.f, 0.f, 0.f, 0.f};

#pragma unroll 1
    for (int ks = 0; ks < 4; ++ks) {
        short8 ahi[4], alo[4];
#pragma unroll
        for (int mt = 0; mt < 4; ++mt) {
            const int row = mt * 16 + lrow;
            const int kc0 = ks * 8 + lkc;
            float4 v0 = ((const float4*)xs)[row * 32 + (kc0 ^ (row & 7))];
            float4 v1 = ((const float4*)xs)[row * 32 + ((kc0 + 1) ^ (row & 7))];
            float e[8];
            e[0] = v0.x; e[1] = v0.y; e[2] = v0.z; e[3] = v0.w;
            e[4] = v1.x; e[5] = v1.y; e[6] = v1.z; e[7] = v1.w;
#pragma unroll
            for (int j = 0; j < 8; ++j) {
                ushort h = (ushort)(__float_as_uint(e[j]) >> 16);   // truncate split
                ahi[mt][j] = (short)h;
                alo[mt][j] = (short)bf16_rne(e[j] - bf16_to_f(h));
            }
        }
#pragma unroll
        for (int nt = 0; nt < 4; ++nt) {
            size_t off = (((size_t)(wave * 4 + nt) * 4 + ks) * 64 + lane) * 8;
            short8 bhi = *(const short8*)&Wfhi[off];
            short8 blo = *(const short8*)&Wflo[off];
#pragma unroll
            for (int mt = 0; mt < 4; ++mt) {
                acc[mt][nt] = __builtin_amdgcn_mfma_f32_16x16x32_bf16(
                    alo[mt], bhi, acc[mt][nt], 0, 0, 0);
                acc[mt][nt] = __builtin_amdgcn_mfma_f32_16x16x32_bf16(
                    ahi[mt], blo, acc[mt][nt], 0, 0, 0);
                acc[mt][nt] = __builtin_amdgcn_mfma_f32_16x16x32_bf16(
                    ahi[mt], bhi, acc[mt][nt], 0, 0, 0);
            }
        }
    }
    // Epilogue. C/D frag: col = lane&15, row = (lane>>4)*4 + i  [m89 layout].
    // Adjacent cols sit in adjacent lanes -> shfl_xor(1) pairs them into a
    // bf16x2 uint; even lanes store. O[row][col/2], low half = even col.
    uint* __restrict__ O = (wave < 2) ? Olb : Orb;
    const int cbase = (wave * 64) & 127;
    const int crow0 = (lane >> 4) * 4;
    const bool evn = (lane & 1) == 0;
#pragma unroll
    for (int mt = 0; mt < 4; ++mt) {
#pragma unroll
        for (int i = 0; i < 4; ++i) {
            const int row = m0 + mt * 16 + crow0 + i;
#pragma unroll
            for (int nt = 0; nt < 4; ++nt) {
                float val = acc[mt][nt][i];
                float pv = __shfl_xor(val, 1);
                uint pk = (uint)bf16_rne(val) | ((uint)bf16_rne(pv) << 16);
                if (evn && row < nrows) {
                    const int col = cbase + nt * 16 + lrow;
                    O[(size_t)row * 64 + (col >> 1)] = pk;
                }
            }
        }
    }
}

// ---------------------------------------------------------------------------
// Fused GATv2 aggregation + bias + ELU + residual + LayerNorm.
// One wave per destination node; static grid-stride. xl/xr are bf16-packed
// (uint = 2 features): halves gather working set and streams.
// ---------------------------------------------------------------------------
__global__ __launch_bounds__(256) void gat_agg(
    const uint* __restrict__ xl, const uint* __restrict__ xr,
    const int* __restrict__ offs, const int* __restrict__ colv,
    const float* __restrict__ att,
    const float* __restrict__ bias, const float* __restrict__ gamma,
    const float* __restrict__ beta, const float* __restrict__ resid,
    float* __restrict__ out, int nnode) {
    const int lane = threadIdx.x & 63;
    const int wave0 = blockIdx.x * 4 + (threadIdx.x >> 6);
    const int wstride = gridDim.x * 4;
    const uint* __restrict__ xlb = xl + lane;
    const f32x2 att2 = ((const f32x2*)att)[lane];
    const f32x2 b2 = ((const f32x2*)bias)[lane];
    const f32x2 g2 = ((const f32x2*)gamma)[lane];
    const f32x2 be2 = ((const f32x2*)beta)[lane];
    for (int gid = wave0; gid < nnode; gid += wstride) {
        const uint xru = __builtin_nontemporal_load(xr + (size_t)gid * 64 + lane);
        const float xrx = __uint_as_float(xru << 16);
        const float xry = __uint_as_float(xru & 0xffff0000u);
        float den = 0.f, acc0 = 0.f, acc1 = 0.f;
        int e = offs[gid];
        const int e1 = offs[gid + 1];
        for (; e + 4 <= e1; e += 4) {   // 4-edge unroll: MLP on the gather
            int s0 = colv[e], s1 = colv[e + 1], s2 = colv[e + 2], s3 = colv[e + 3];
            uint u0 = xlb[(size_t)s0 * 64];
            uint u1 = xlb[(size_t)s1 * 64];
            uint u2 = xlb[(size_t)s2 * 64];
            uint u3 = xlb[(size_t)s3 * 64];
            float a0x = __uint_as_float(u0 << 16), a0y = __uint_as_float(u0 & 0xffff0000u);
            float a1x = __uint_as_float(u1 << 16), a1y = __uint_as_float(u1 & 0xffff0000u);
            float a2x = __uint_as_float(u2 << 16), a2y = __uint_as_float(u2 & 0xffff0000u);
            float a3x = __uint_as_float(u3 << 16), a3y = __uint_as_float(u3 & 0xffff0000u);
            float m0x = a0x + xrx, m0y = a0y + xry;
            float m1x = a1x + xrx, m1y = a1y + xry;
            float m2x = a2x + xrx, m2y = a2y + xry;
            float m3x = a3x + xrx, m3y = a3y + xry;
            m0x = fmaxf(m0x, LEAKY * m0x); m0y = fmaxf(m0y, LEAKY * m0y);
            m1x = fmaxf(m1x, LEAKY * m1x); m1y = fmaxf(m1y, LEAKY * m1y);
            m2x = fmaxf(m2x, LEAKY * m2x); m2y = fmaxf(m2y, LEAKY * m2y);
            m3x = fmaxf(m3x, LEAKY * m3x); m3y = fmaxf(m3y, LEAKY * m3y);
            float p0 = m0x * att2.x + m0y * att2.y;
            float p1 = m1x * att2.x + m1y * att2.y;
            float p2 = m2x * att2.x + m2y * att2.y;
            float p3 = m3x * att2.x + m3y * att2.y;
            p0 += __shfl_xor(p0, 1); p0 += __shfl_xor(p0, 2); p0 += __shfl_xor(p0, 4);
            p1 += __shfl_xor(p1, 1); p1 += __shfl_xor(p1, 2); p1 += __shfl_xor(p1, 4);
            p2 += __shfl_xor(p2, 1); p2 += __shfl_xor(p2, 2); p2 += __shfl_xor(p2, 4);
            p3 += __shfl_xor(p3, 1); p3 += __shfl_xor(p3, 2); p3 += __shfl_xor(p3, 4);
            float ex0 = __expf(p0), ex1 = __expf(p1);
            float ex2 = __expf(p2), ex3 = __expf(p3);
            den += (ex0 + ex1) + (ex2 + ex3);
            acc0 += a0x * ex0 + a1x * ex1 + a2x * ex2 + a3x * ex3;
            acc1 += a0y * ex0 + a1y * ex1 + a2y * ex2 + a3y * ex3;
        }
        for (; e < e1; ++e) {
            int s0 = colv[e];
            uint u0 = xlb[(size_t)s0 * 64];
            float a0x = __uint_as_float(u0 << 16), a0y = __uint_as_float(u0 & 0xffff0000u);
            float m0x = a0x + xrx, m0y = a0y + xry;
            m0x = fmaxf(m0x, LEAKY * m0x);
            m0y = fmaxf(m0y, LEAKY * m0y);
            float p0 = m0x * att2.x + m0y * att2.y;
            p0 += __shfl_xor(p0, 1); p0 += __shfl_xor(p0, 2); p0 += __shfl_xor(p0, 4);
            float ex0 = __expf(p0);
            den += ex0;
            acc0 += a0x * ex0;
            acc1 += a0y * ex0;
        }
        float inv_den = 1.f / den;
        float v0 = acc0 * inv_den + b2.x;
        float v1 = acc1 * inv_den + b2.y;
        v0 = v0 > 0.f ? v0 : expm1f(v0);     // ELU (alpha=1)
        v1 = v1 > 0.f ? v1 : expm1f(v1);
        const f32x2 r2 = __builtin_nontemporal_load(
            (const f32x2*)resid + (size_t)gid * 64 + lane);
        float t0 = v0 + r2.x, t1 = v1 + r2.y;
        float s = t0 + t1, ss = t0 * t0 + t1 * t1;
#pragma unroll
        for (int m = 1; m < 64; m <<= 1) {
            s += __shfl_xor(s, m);
            ss += __shfl_xor(ss, m);
        }
        const float mu = s * 0.0078125f;
        const float var = ss * 0.0078125f - mu * mu;
        const float iv = rsqrtf(var + LN_EPS);
        f32x2 o;
        o.x = (t0 - mu) * iv * g2.x + be2.x;
        o.y = (t1 - mu) * iv * g2.y + be2.y;
        __builtin_nontemporal_store(o, (f32x2*)out + (size_t)gid * 64 + lane);
    }
}

// ---------------------------------------------------------------------------
extern "C" void kernel_launch(void* const* d_in, const int* in_sizes, int n_in,
                              void* d_out, int out_size, void* d_ws, size_t ws_size,
                              hipStream_t stream) {
    const float* x   = (const float*)d_in[0];
    const int*   ei  = (const int*)d_in[1];
    const float* Wl0 = (const float*)d_in[2];
    const float* Wr0 = (const float*)d_in[3];
    const float* at0 = (const float*)d_in[4];
    const float* b0  = (const float*)d_in[5];
    const float* g0  = (const float*)d_in[6];
    const float* be0 = (const float*)d_in[7];
    const float* Wl1 = (const float*)d_in[8];
    const float* Wr1 = (const float*)d_in[9];
    const float* at1 = (const float*)d_in[10];
    const float* b1  = (const float*)d_in[11];
    const float* g1  = (const float*)d_in[12];
    const float* be1 = (const float*)d_in[13];

    const int NF = in_sizes[0];        // N*128
    const int n  = NF / 128;           // nodes
    const int er = in_sizes[1] / 2;    // raw edges
    const int etot = er + n;           // + self-loops
    const int nb = (n + 1023) / 1024;  // scan blocks

    uint* A     = (uint*)d_ws;         // xl bf16-packed (N*64 uints)
    uint* B     = A + (size_t)NF / 2;  // xr bf16-packed
    ushort* Whi = (ushort*)(B + (size_t)NF / 2);   // [2][32768] bf16 hi
    ushort* Wlo = Whi + 65536;                     // [2][32768] bf16 lo
    int* deg    = (int*)(Wlo + 65536);
    int* woff   = deg + n;
    int* offs   = woff + n;
    int* escan  = offs + (n + 1);
    int* bsum   = escan + n;
    int* bpre   = bsum + 1024;
    int* colv   = bpre + 1024;
    float* C    = (float*)d_out;       // layer-1 output / residual / final out

    // ---- CSR build (shared by both layers) + both W conversions ----
    (void)hipMemsetAsync(deg, 0, (size_t)n * sizeof(int), stream);
    hist_kernel<<<(etot + 255) / 256, 256, 0, stream>>>(ei, er, etot, deg);
    scanA<<<nb, 1024, 0, stream>>>(deg, escan, bsum, n);
    scanB<<<1, 1024, 0, stream>>>(bsum, bpre, nb, offs, n);
    scanC<<<(n + 255) / 256, 256, 0, stream>>>(escan, bpre, offs, woff, n);
    fill_kernel<<<(etot + 255) / 256, 256, 0, stream>>>(ei, er, etot, woff, colv);
    cvt_w2<<<256, 256, 0, stream>>>(Wl0, Wr0, Wl1, Wr1, Whi, Wlo);

    const int gblk = (n + 63) / 64;

    // ---- layer 1 ----
    gemm_mfma<<<gblk, 256, 0, stream>>>(x, Whi, Wlo, A, B, n);
    gat_agg<<<2048, 256, 0, stream>>>(A, B, offs, colv, at0, b0, g0, be0,
                                      x, C, n);
    // ---- layer 2 ----
    gemm_mfma<<<gblk, 256, 0, stream>>>(C, Whi + 32768, Wlo + 32768, A, B, n);
    gat_agg<<<2048, 256, 0, stream>>>(A, B, offs, colv, at1, b1, g1, be1,
                                      C, C, n);
}

// Round 12
// 470.535 us; speedup vs baseline: 1.2554x; 1.1209x over previous
//
#include <hip/hip_runtime.h>
#include <cstdint>

#define LEAKY 0.2f
#define LN_EPS 1e-5f

typedef __attribute__((ext_vector_type(8))) short short8;   // 8 x bf16 (4 VGPR)
typedef __attribute__((ext_vector_type(4))) float f32x4;    // MFMA accum
typedef __attribute__((ext_vector_type(2))) float f32x2;    // NT-compatible float2

__device__ __forceinline__ ushort bf16_rne(float x) {
    unsigned u = __float_as_uint(x);
    unsigned r = (u + 0x7fffu + ((u >> 16) & 1u)) >> 16;
    return (ushort)r;
}
__device__ __forceinline__ float bf16_to_f(ushort h) {
    return __uint_as_float(((unsigned)h) << 16);
}

// ---------------------------------------------------------------------------
// CSR build, XCD-partitioned: blocks with (blockIdx&7)==x own dst range
// [n*x/8, n*(x+1)/8). All atomics/writes to a given cacheline then come from
// one XCD -> no cross-XCD L2 ping-pong (round-11 fill: 108MB writes for a
// 6.8MB array). Mapping bid->XCD is a heuristic; correctness is independent.
// ---------------------------------------------------------------------------
__global__ void hist_part(const int* __restrict__ ei, int er, int etot, int n,
                          int* __restrict__ deg) {
    const int xcd = blockIdx.x & 7;
    const int lo = (int)((long long)n * xcd >> 3);
    const int hi = (int)((long long)n * (xcd + 1) >> 3);
    const int stride = (gridDim.x >> 3) * blockDim.x;
    for (int e = (blockIdx.x >> 3) * blockDim.x + threadIdx.x; e < etot;
         e += stride) {
        int dst = (e < er) ? ei[er + e] : (e - er);
        if (dst >= lo && dst < hi) atomicAdd(&deg[dst], 1);
    }
}

__global__ void fill_part(const int* __restrict__ ei, int er, int etot, int n,
                          int* __restrict__ woff, int* __restrict__ colv) {
    const int xcd = blockIdx.x & 7;
    const int lo = (int)((long long)n * xcd >> 3);
    const int hi = (int)((long long)n * (xcd + 1) >> 3);
    const int stride = (gridDim.x >> 3) * blockDim.x;
    for (int e = (blockIdx.x >> 3) * blockDim.x + threadIdx.x; e < etot;
         e += stride) {
        int dst = (e < er) ? ei[er + e] : (e - er);
        if (dst >= lo && dst < hi) {
            int src = (e < er) ? ei[e] : dst;
            int pos = atomicAdd(&woff[dst], 1);
            colv[pos] = src;
        }
    }
}

__global__ __launch_bounds__(1024) void scanA(const int* __restrict__ deg,
                                              int* __restrict__ escan,
                                              int* __restrict__ bsum, int n) {
    __shared__ int wsum[16], wpre[16];
    const int lane = threadIdx.x & 63, wv = threadIdx.x >> 6;
    const int i = blockIdx.x * 1024 + threadIdx.x;
    int v = (i < n) ? deg[i] : 0;
    int x = v;
#pragma unroll
    for (int off = 1; off < 64; off <<= 1) {
        int y = __shfl_up(x, off, 64);
        if (lane >= off) x += y;
    }
    if (lane == 63) wsum[wv] = x;
    __syncthreads();
    if (wv == 0) {
        int s = (lane < 16) ? wsum[lane] : 0;
#pragma unroll
        for (int off = 1; off < 16; off <<= 1) {
            int y = __shfl_up(s, off, 64);
            if (lane >= off) s += y;
        }
        if (lane < 16) wpre[lane] = s;
    }
    __syncthreads();
    int excl = x - v + (wv ? wpre[wv - 1] : 0);
    if (i < n) escan[i] = excl;
    if (threadIdx.x == 1023) bsum[blockIdx.x] = wpre[15];
}

__global__ __launch_bounds__(1024) void scanB(const int* __restrict__ bsum,
                                              int* __restrict__ bpre, int nb,
                                              int* __restrict__ offs, int n) {
    __shared__ int wsum[16], wpre[16];
    const int lane = threadIdx.x & 63, wv = threadIdx.x >> 6;
    const int i = threadIdx.x;
    int v = (i < nb) ? bsum[i] : 0;
    int x = v;
#pragma unroll
    for (int off = 1; off < 64; off <<= 1) {
        int y = __shfl_up(x, off, 64);
        if (lane >= off) x += y;
    }
    if (lane == 63) wsum[wv] = x;
    __syncthreads();
    if (wv == 0) {
        int s = (lane < 16) ? wsum[lane] : 0;
#pragma unroll
        for (int off = 1; off < 16; off <<= 1) {
            int y = __shfl_up(s, off, 64);
            if (lane >= off) s += y;
        }
        if (lane < 16) wpre[lane] = s;
    }
    __syncthreads();
    if (i < nb) bpre[i] = x - v + (wv ? wpre[wv - 1] : 0);
    if (threadIdx.x == 1023) offs[n] = wpre[15];
}

__global__ void scanC(const int* __restrict__ escan, const int* __restrict__ bpre,
                      int* __restrict__ offs, int* __restrict__ woff, int n) {
    int i = blockIdx.x * 256 + threadIdx.x;
    if (i >= n) return;
    int o = escan[i] + bpre[i >> 10];
    offs[i] = o;
    woff[i] = o;
}

// ---------------------------------------------------------------------------
// Both layers' W -> per-MFMA-fragment bf16 hi/lo layout (one dispatch).
// ---------------------------------------------------------------------------
__global__ void cvt_w2(const float* __restrict__ Wl0, const float* __restrict__ Wr0,
                       const float* __restrict__ Wl1, const float* __restrict__ Wr1,
                       ushort* __restrict__ Whi, ushort* __restrict__ Wlo) {
    int t = blockIdx.x * 256 + threadIdx.x;     // 0..65535
    int layer = t >> 15;
    int i = t & 32767;
    int colblk = i >> 11;
    int ks = (i >> 9) & 3;
    int lane = (i >> 3) & 63;
    int j = i & 7;
    int col = colblk * 16 + (lane & 15);
    int k = ks * 32 + (lane >> 4) * 8 + j;
    const float* Wl = layer ? Wl1 : Wl0;
    const float* Wr = layer ? Wr1 : Wr0;
    float v = (col < 128) ? Wl[(size_t)k * 128 + col]
                          : Wr[(size_t)k * 128 + (col - 128)];
    ushort h = bf16_rne(v);
    Whi[t] = h;
    Wlo[t] = bf16_rne(v - bf16_to_f(h));
}

// ---------------------------------------------------------------------------
// Dual GEMM via split-bf16 MFMA. Block = 4 waves, 64-row tile.
// Output packed to bf16 pairs (uint) via shfl_xor lane-pairing.
// ---------------------------------------------------------------------------
__global__ __launch_bounds__(256) void gemm_mfma(
    const float* __restrict__ X,
    const ushort* __restrict__ Wfhi, const ushort* __restrict__ Wflo,
    uint* __restrict__ Olb, uint* __restrict__ Orb, int nrows) {
    __shared__ float xs[64 * 32 * 4];           // 32 KiB, float4 slot = row*32 + (kc^(row&7))
    const int t = threadIdx.x;
    const int wave = t >> 6, lane = t & 63;
    const int m0 = blockIdx.x * 64;
    {   // stage X tile: 2048 float4, 8 per thread, coalesced
        const float4* Xv = (const float4*)X + (size_t)m0 * 32;
        float4* xsv = (float4*)xs;
#pragma unroll
        for (int i = 0; i < 8; ++i) {
            int idx = i * 256 + t;
            int row = idx >> 5, kc = idx & 31;
            float4 v = {0.f, 0.f, 0.f, 0.f};
            if (m0 + row < nrows) v = Xv[idx];
            xsv[row * 32 + (kc ^ (row & 7))] = v;
        }
    }
    __syncthreads();

    const int lrow = lane & 15;
    const int lkc = (lane >> 4) * 2;            // 16B-slot offset within ks block
    f32x4 acc[4][4];
#pragma unroll
    for (int mt = 0; mt < 4; ++mt)
#pragma unroll
        for (int nt = 0; nt < 4; ++nt) acc[mt][nt] = (f32x4){0.f, 0.f, 0.f, 0.f};

#pragma unroll 1
    for (int ks = 0; ks < 4; ++ks) {
        short8 ahi[4], alo[4];
#pragma unroll
        for (int mt = 0; mt < 4; ++mt) {
            const int row = mt * 16 + lrow;
            const int kc0 = ks * 8 + lkc;
            float4 v0 = ((const float4*)xs)[row * 32 + (kc0 ^ (row & 7))];
            float4 v1 = ((const float4*)xs)[row * 32 + ((kc0 + 1) ^ (row & 7))];
            float e[8];
            e[0] = v0.x; e[1] = v0.y; e[2] = v0.z; e[3] = v0.w;
            e[4] = v1.x; e[5] = v1.y; e[6] = v1.z; e[7] = v1.w;
#pragma unroll
            for (int j = 0; j < 8; ++j) {
                ushort h = (ushort)(__float_as_uint(e[j]) >> 16);   // truncate split
                ahi[mt][j] = (short)h;
                alo[mt][j] = (short)bf16_rne(e[j] - bf16_to_f(h));
            }
        }
#pragma unroll
        for (int nt = 0; nt < 4; ++nt) {
            size_t off = (((size_t)(wave * 4 + nt) * 4 + ks) * 64 + lane) * 8;
            short8 bhi = *(const short8*)&Wfhi[off];
            short8 blo = *(const short8*)&Wflo[off];
#pragma unroll
            for (int mt = 0; mt < 4; ++mt) {
                acc[mt][nt] = __builtin_amdgcn_mfma_f32_16x16x32_bf16(
                    alo[mt], bhi, acc[mt][nt], 0, 0, 0);
                acc[mt][nt] = __builtin_amdgcn_mfma_f32_16x16x32_bf16(
                    ahi[mt], blo, acc[mt][nt], 0, 0, 0);
                acc[mt][nt] = __builtin_amdgcn_mfma_f32_16x16x32_bf16(
                    ahi[mt], bhi, acc[mt][nt], 0, 0, 0);
            }
        }
    }
    // Epilogue. C/D frag: col = lane&15, row = (lane>>4)*4 + i  [m89 layout].
    uint* __restrict__ O = (wave < 2) ? Olb : Orb;
    const int cbase = (wave * 64) & 127;
    const int crow0 = (lane >> 4) * 4;
    const bool evn = (lane & 1) == 0;
#pragma unroll
    for (int mt = 0; mt < 4; ++mt) {
#pragma unroll
        for (int i = 0; i < 4; ++i) {
            const int row = m0 + mt * 16 + crow0 + i;
#pragma unroll
            for (int nt = 0; nt < 4; ++nt) {
                float val = acc[mt][nt][i];
                float pv = __shfl_xor(val, 1);
                uint pk = (uint)bf16_rne(val) | ((uint)bf16_rne(pv) << 16);
                if (evn && row < nrows) {
                    const int col = cbase + nt * 16 + lrow;
                    O[(size_t)row * 64 + (col >> 1)] = pk;
                }
            }
        }
    }
}

// ---------------------------------------------------------------------------
// Fused GATv2 aggregation + bias + ELU + residual + LayerNorm.
// One wave per destination node; static grid-stride; bf16-packed xl/xr.
// ---------------------------------------------------------------------------
__global__ __launch_bounds__(256) void gat_agg(
    const uint* __restrict__ xl, const uint* __restrict__ xr,
    const int* __restrict__ offs, const int* __restrict__ colv,
    const float* __restrict__ att,
    const float* __restrict__ bias, const float* __restrict__ gamma,
    const float* __restrict__ beta, const float* __restrict__ resid,
    float* __restrict__ out, int nnode) {
    const int lane = threadIdx.x & 63;
    const int wave0 = blockIdx.x * 4 + (threadIdx.x >> 6);
    const int wstride = gridDim.x * 4;
    const uint* __restrict__ xlb = xl + lane;
    const f32x2 att2 = ((const f32x2*)att)[lane];
    const f32x2 b2 = ((const f32x2*)bias)[lane];
    const f32x2 g2 = ((const f32x2*)gamma)[lane];
    const f32x2 be2 = ((const f32x2*)beta)[lane];
    for (int gid = wave0; gid < nnode; gid += wstride) {
        const uint xru = __builtin_nontemporal_load(xr + (size_t)gid * 64 + lane);
        const float xrx = __uint_as_float(xru << 16);
        const float xry = __uint_as_float(xru & 0xffff0000u);
        float den = 0.f, acc0 = 0.f, acc1 = 0.f;
        int e = offs[gid];
        const int e1 = offs[gid + 1];
        for (; e + 4 <= e1; e += 4) {   // 4-edge unroll: MLP on the gather
            int s0 = colv[e], s1 = colv[e + 1], s2 = colv[e + 2], s3 = colv[e + 3];
            uint u0 = xlb[(size_t)s0 * 64];
            uint u1 = xlb[(size_t)s1 * 64];
            uint u2 = xlb[(size_t)s2 * 64];
            uint u3 = xlb[(size_t)s3 * 64];
            float a0x = __uint_as_float(u0 << 16), a0y = __uint_as_float(u0 & 0xffff0000u);
            float a1x = __uint_as_float(u1 << 16), a1y = __uint_as_float(u1 & 0xffff0000u);
            float a2x = __uint_as_float(u2 << 16), a2y = __uint_as_float(u2 & 0xffff0000u);
            float a3x = __uint_as_float(u3 << 16), a3y = __uint_as_float(u3 & 0xffff0000u);
            float m0x = a0x + xrx, m0y = a0y + xry;
            float m1x = a1x + xrx, m1y = a1y + xry;
            float m2x = a2x + xrx, m2y = a2y + xry;
            float m3x = a3x + xrx, m3y = a3y + xry;
            m0x = fmaxf(m0x, LEAKY * m0x); m0y = fmaxf(m0y, LEAKY * m0y);
            m1x = fmaxf(m1x, LEAKY * m1x); m1y = fmaxf(m1y, LEAKY * m1y);
            m2x = fmaxf(m2x, LEAKY * m2x); m2y = fmaxf(m2y, LEAKY * m2y);
            m3x = fmaxf(m3x, LEAKY * m3x); m3y = fmaxf(m3y, LEAKY * m3y);
            float p0 = m0x * att2.x + m0y * att2.y;
            float p1 = m1x * att2.x + m1y * att2.y;
            float p2 = m2x * att2.x + m2y * att2.y;
            float p3 = m3x * att2.x + m3y * att2.y;
            p0 += __shfl_xor(p0, 1); p0 += __shfl_xor(p0, 2); p0 += __shfl_xor(p0, 4);
            p1 += __shfl_xor(p1, 1); p1 += __shfl_xor(p1, 2); p1 += __shfl_xor(p1, 4);
            p2 += __shfl_xor(p2, 1); p2 += __shfl_xor(p2, 2); p2 += __shfl_xor(p2, 4);
            p3 += __shfl_xor(p3, 1); p3 += __shfl_xor(p3, 2); p3 += __shfl_xor(p3, 4);
            float ex0 = __expf(p0), ex1 = __expf(p1);
            float ex2 = __expf(p2), ex3 = __expf(p3);
            den += (ex0 + ex1) + (ex2 + ex3);
            acc0 += a0x * ex0 + a1x * ex1 + a2x * ex2 + a3x * ex3;
            acc1 += a0y * ex0 + a1y * ex1 + a2y * ex2 + a3y * ex3;
        }
        for (; e < e1; ++e) {
            int s0 = colv[e];
            uint u0 = xlb[(size_t)s0 * 64];
            float a0x = __uint_as_float(u0 << 16), a0y = __uint_as_float(u0 & 0xffff0000u);
            float m0x = a0x + xrx, m0y = a0y + xry;
            m0x = fmaxf(m0x, LEAKY * m0x);
            m0y = fmaxf(m0y, LEAKY * m0y);
            float p0 = m0x * att2.x + m0y * att2.y;
            p0 += __shfl_xor(p0, 1); p0 += __shfl_xor(p0, 2); p0 += __shfl_xor(p0, 4);
            float ex0 = __expf(p0);
            den += ex0;
            acc0 += a0x * ex0;
            acc1 += a0y * ex0;
        }
        float inv_den = 1.f / den;
        float v0 = acc0 * inv_den + b2.x;
        float v1 = acc1 * inv_den + b2.y;
        v0 = v0 > 0.f ? v0 : expm1f(v0);     // ELU (alpha=1)
        v1 = v1 > 0.f ? v1 : expm1f(v1);
        const f32x2 r2 = __builtin_nontemporal_load(
            (const f32x2*)resid + (size_t)gid * 64 + lane);
        float t0 = v0 + r2.x, t1 = v1 + r2.y;
        float s = t0 + t1, ss = t0 * t0 + t1 * t1;
#pragma unroll
        for (int m = 1; m < 64; m <<= 1) {
            s += __shfl_xor(s, m);
            ss += __shfl_xor(ss, m);
        }
        const float mu = s * 0.0078125f;
        const float var = ss * 0.0078125f - mu * mu;
        const float iv = rsqrtf(var + LN_EPS);
        f32x2 o;
        o.x = (t0 - mu) * iv * g2.x + be2.x;
        o.y = (t1 - mu) * iv * g2.y + be2.y;
        __builtin_nontemporal_store(o, (f32x2*)out + (size_t)gid * 64 + lane);
    }
}

// ---------------------------------------------------------------------------
extern "C" void kernel_launch(void* const* d_in, const int* in_sizes, int n_in,
                              void* d_out, int out_size, void* d_ws, size_t ws_size,
                              hipStream_t stream) {
    const float* x   = (const float*)d_in[0];
    const int*   ei  = (const int*)d_in[1];
    const float* Wl0 = (const float*)d_in[2];
    const float* Wr0 = (const float*)d_in[3];
    const float* at0 = (const float*)d_in[4];
    const float* b0  = (const float*)d_in[5];
    const float* g0  = (const float*)d_in[6];
    const float* be0 = (const float*)d_in[7];
    const float* Wl1 = (const float*)d_in[8];
    const float* Wr1 = (const float*)d_in[9];
    const float* at1 = (const float*)d_in[10];
    const float* b1  = (const float*)d_in[11];
    const float* g1  = (const float*)d_in[12];
    const float* be1 = (const float*)d_in[13];

    const int NF = in_sizes[0];        // N*128
    const int n  = NF / 128;           // nodes
    const int er = in_sizes[1] / 2;    // raw edges
    const int etot = er + n;           // + self-loops
    const int nb = (n + 1023) / 1024;  // scan blocks

    uint* A     = (uint*)d_ws;         // xl bf16-packed (N*64 uints)
    uint* B     = A + (size_t)NF / 2;  // xr bf16-packed
    ushort* Whi = (ushort*)(B + (size_t)NF / 2);   // [2][32768] bf16 hi
    ushort* Wlo = Whi + 65536;                     // [2][32768] bf16 lo
    int* deg    = (int*)(Wlo + 65536);
    int* woff   = deg + n;
    int* offs   = woff + n;
    int* escan  = offs + (n + 1);
    int* bsum   = escan + n;
    int* bpre   = bsum + 1024;
    int* colv   = bpre + 1024;
    float* C    = (float*)d_out;       // layer-1 output / residual / final out

    // ---- CSR build (XCD-partitioned) + both W conversions ----
    (void)hipMemsetAsync(deg, 0, (size_t)n * sizeof(int), stream);
    hist_part<<<2048, 256, 0, stream>>>(ei, er, etot, n, deg);
    scanA<<<nb, 1024, 0, stream>>>(deg, escan, bsum, n);
    scanB<<<1, 1024, 0, stream>>>(bsum, bpre, nb, offs, n);
    scanC<<<(n + 255) / 256, 256, 0, stream>>>(escan, bpre, offs, woff, n);
    fill_part<<<2048, 256, 0, stream>>>(ei, er, etot, n, woff, colv);
    cvt_w2<<<256, 256, 0, stream>>>(Wl0, Wr0, Wl1, Wr1, Whi, Wlo);

    const int gblk = (n + 63) / 64;

    // ---- layer 1 ----
    gemm_mfma<<<gblk, 256, 0, stream>>>(x, Whi, Wlo, A, B, n);
    gat_agg<<<2048, 256, 0, stream>>>(A, B, offs, colv, at0, b0, g0, be0,
                                      x, C, n);
    // ---- layer 2 ----
    gemm_mfma<<<gblk, 256, 0, stream>>>(C, Whi + 32768, Wlo + 32768, A, B, n);
    gat_agg<<<2048, 256, 0, stream>>>(A, B, offs, colv, at1, b1, g1, be1,
                                      C, C, n);
}

// Round 13
// 445.356 us; speedup vs baseline: 1.3264x; 1.0565x over previous
//
#include <hip/hip_runtime.h>
#include <cstdint>

#define LEAKY 0.2f
#define LN_EPS 1e-5f

typedef __attribute__((ext_vector_type(8))) short short8;   // 8 x bf16 (4 VGPR)
typedef __attribute__((ext_vector_type(4))) float f32x4;    // MFMA accum
typedef __attribute__((ext_vector_type(2))) float f32x2;

__device__ __forceinline__ ushort bf16_rne(float x) {
    unsigned u = __float_as_uint(x);
    unsigned r = (u + 0x7fffu + ((u >> 16) & 1u)) >> 16;
    return (ushort)r;
}
__device__ __forceinline__ float bf16_to_f(ushort h) {
    return __uint_as_float(((unsigned)h) << 16);
}
__device__ __forceinline__ f32x2 unpk(uint u) {
    f32x2 r;
    r.x = __uint_as_float(u << 16);
    r.y = __uint_as_float(u & 0xffff0000u);
    return r;
}

// ---------------------------------------------------------------------------
// CSR build, XCD-partitioned (round-12 win: no cross-XCD cacheline ping-pong)
// ---------------------------------------------------------------------------
__global__ void hist_part(const int* __restrict__ ei, int er, int etot, int n,
                          int* __restrict__ deg) {
    const int xcd = blockIdx.x & 7;
    const int lo = (int)((long long)n * xcd >> 3);
    const int hi = (int)((long long)n * (xcd + 1) >> 3);
    const int stride = (gridDim.x >> 3) * blockDim.x;
    for (int e = (blockIdx.x >> 3) * blockDim.x + threadIdx.x; e < etot;
         e += stride) {
        int dst = (e < er) ? ei[er + e] : (e - er);
        if (dst >= lo && dst < hi) atomicAdd(&deg[dst], 1);
    }
}

__global__ void fill_part(const int* __restrict__ ei, int er, int etot, int n,
                          int* __restrict__ woff, int* __restrict__ colv) {
    const int xcd = blockIdx.x & 7;
    const int lo = (int)((long long)n * xcd >> 3);
    const int hi = (int)((long long)n * (xcd + 1) >> 3);
    const int stride = (gridDim.x >> 3) * blockDim.x;
    for (int e = (blockIdx.x >> 3) * blockDim.x + threadIdx.x; e < etot;
         e += stride) {
        int dst = (e < er) ? ei[er + e] : (e - er);
        if (dst >= lo && dst < hi) {
            int src = (e < er) ? ei[e] : dst;
            int pos = atomicAdd(&woff[dst], 1);
            colv[pos] = src;
        }
    }
}

__global__ __launch_bounds__(1024) void scanA(const int* __restrict__ deg,
                                              int* __restrict__ escan,
                                              int* __restrict__ bsum, int n) {
    __shared__ int wsum[16], wpre[16];
    const int lane = threadIdx.x & 63, wv = threadIdx.x >> 6;
    const int i = blockIdx.x * 1024 + threadIdx.x;
    int v = (i < n) ? deg[i] : 0;
    int x = v;
#pragma unroll
    for (int off = 1; off < 64; off <<= 1) {
        int y = __shfl_up(x, off, 64);
        if (lane >= off) x += y;
    }
    if (lane == 63) wsum[wv] = x;
    __syncthreads();
    if (wv == 0) {
        int s = (lane < 16) ? wsum[lane] : 0;
#pragma unroll
        for (int off = 1; off < 16; off <<= 1) {
            int y = __shfl_up(s, off, 64);
            if (lane >= off) s += y;
        }
        if (lane < 16) wpre[lane] = s;
    }
    __syncthreads();
    int excl = x - v + (wv ? wpre[wv - 1] : 0);
    if (i < n) escan[i] = excl;
    if (threadIdx.x == 1023) bsum[blockIdx.x] = wpre[15];
}

__global__ __launch_bounds__(1024) void scanB(const int* __restrict__ bsum,
                                              int* __restrict__ bpre, int nb,
                                              int* __restrict__ offs, int n) {
    __shared__ int wsum[16], wpre[16];
    const int lane = threadIdx.x & 63, wv = threadIdx.x >> 6;
    const int i = threadIdx.x;
    int v = (i < nb) ? bsum[i] : 0;
    int x = v;
#pragma unroll
    for (int off = 1; off < 64; off <<= 1) {
        int y = __shfl_up(x, off, 64);
        if (lane >= off) x += y;
    }
    if (lane == 63) wsum[wv] = x;
    __syncthreads();
    if (wv == 0) {
        int s = (lane < 16) ? wsum[lane] : 0;
#pragma unroll
        for (int off = 1; off < 16; off <<= 1) {
            int y = __shfl_up(s, off, 64);
            if (lane >= off) s += y;
        }
        if (lane < 16) wpre[lane] = s;
    }
    __syncthreads();
    if (i < nb) bpre[i] = x - v + (wv ? wpre[wv - 1] : 0);
    if (threadIdx.x == 1023) offs[n] = wpre[15];
}

__global__ void scanC(const int* __restrict__ escan, const int* __restrict__ bpre,
                      int* __restrict__ offs, int* __restrict__ woff, int n) {
    int i = blockIdx.x * 256 + threadIdx.x;
    if (i >= n) return;
    int o = escan[i] + bpre[i >> 10];
    offs[i] = o;
    woff[i] = o;
}

// ---------------------------------------------------------------------------
// Both layers' W -> per-MFMA-fragment bf16 hi/lo layout (one dispatch).
// ---------------------------------------------------------------------------
__global__ void cvt_w2(const float* __restrict__ Wl0, const float* __restrict__ Wr0,
                       const float* __restrict__ Wl1, const float* __restrict__ Wr1,
                       ushort* __restrict__ Whi, ushort* __restrict__ Wlo) {
    int t = blockIdx.x * 256 + threadIdx.x;     // 0..65535
    int layer = t >> 15;
    int i = t & 32767;
    int colblk = i >> 11;
    int ks = (i >> 9) & 3;
    int lane = (i >> 3) & 63;
    int j = i & 7;
    int col = colblk * 16 + (lane & 15);
    int k = ks * 32 + (lane >> 4) * 8 + j;
    const float* Wl = layer ? Wl1 : Wl0;
    const float* Wr = layer ? Wr1 : Wr0;
    float v = (col < 128) ? Wl[(size_t)k * 128 + col]
                          : Wr[(size_t)k * 128 + (col - 128)];
    ushort h = bf16_rne(v);
    Whi[t] = h;
    Wlo[t] = bf16_rne(v - bf16_to_f(h));
}

// ---------------------------------------------------------------------------
// Dual GEMM. A-input either fp32 (split-bf16, 3 MFMA) or packed bf16
// (exact, 2 MFMA + half the read). Output packed bf16 pairs.
// ---------------------------------------------------------------------------
template <bool ABF16>
__global__ __launch_bounds__(256) void gemm_mfma(
    const void* __restrict__ Xin,
    const ushort* __restrict__ Wfhi, const ushort* __restrict__ Wflo,
    uint* __restrict__ Olb, uint* __restrict__ Orb, int nrows) {
    __shared__ float4 xs[64 * 32];              // 32 KiB (fp32) / 16 KiB used (bf16)
    const int t = threadIdx.x;
    const int wave = t >> 6, lane = t & 63;
    const int m0 = blockIdx.x * 64;
    if (ABF16) {
        const uint4* Xv = (const uint4*)Xin + (size_t)m0 * 16;
        uint4* xsb = (uint4*)xs;
#pragma unroll
        for (int i = 0; i < 4; ++i) {
            int idx = i * 256 + t;
            int row = idx >> 4, kc = idx & 15;
            uint4 v = {0u, 0u, 0u, 0u};
            if (m0 + row < nrows) v = Xv[idx];
            xsb[row * 16 + (kc ^ (row & 7))] = v;
        }
    } else {
        const float4* Xv = (const float4*)Xin + (size_t)m0 * 32;
#pragma unroll
        for (int i = 0; i < 8; ++i) {
            int idx = i * 256 + t;
            int row = idx >> 5, kc = idx & 31;
            float4 v = {0.f, 0.f, 0.f, 0.f};
            if (m0 + row < nrows) v = Xv[idx];
            xs[row * 32 + (kc ^ (row & 7))] = v;
        }
    }
    __syncthreads();

    const int lrow = lane & 15;
    const int lkc = (lane >> 4) * 2;
    f32x4 acc[4][4];
#pragma unroll
    for (int mt = 0; mt < 4; ++mt)
#pragma unroll
        for (int nt = 0; nt < 4; ++nt) acc[mt][nt] = (f32x4){0.f, 0.f, 0.f, 0.f};

#pragma unroll 1
    for (int ks = 0; ks < 4; ++ks) {
        short8 ahi[4], alo[4];
#pragma unroll
        for (int mt = 0; mt < 4; ++mt) {
            const int row = mt * 16 + lrow;
            if (ABF16) {
                const int slot = ks * 4 + (lane >> 4);
                uint4 w = ((const uint4*)xs)[row * 16 + (slot ^ (row & 7))];
                ahi[mt] = *(const short8*)&w;
            } else {
                const int kc0 = ks * 8 + lkc;
                float4 v0 = xs[row * 32 + (kc0 ^ (row & 7))];
                float4 v1 = xs[row * 32 + ((kc0 + 1) ^ (row & 7))];
                float e[8];
                e[0] = v0.x; e[1] = v0.y; e[2] = v0.z; e[3] = v0.w;
                e[4] = v1.x; e[5] = v1.y; e[6] = v1.z; e[7] = v1.w;
#pragma unroll
                for (int j = 0; j < 8; ++j) {
                    ushort h = (ushort)(__float_as_uint(e[j]) >> 16);  // trunc split
                    ahi[mt][j] = (short)h;
                    alo[mt][j] = (short)bf16_rne(e[j] - bf16_to_f(h));
                }
            }
        }
#pragma unroll
        for (int nt = 0; nt < 4; ++nt) {
            size_t off = (((size_t)(wave * 4 + nt) * 4 + ks) * 64 + lane) * 8;
            short8 bhi = *(const short8*)&Wfhi[off];
            short8 blo = *(const short8*)&Wflo[off];
#pragma unroll
            for (int mt = 0; mt < 4; ++mt) {
                if (!ABF16)
                    acc[mt][nt] = __builtin_amdgcn_mfma_f32_16x16x32_bf16(
                        alo[mt], bhi, acc[mt][nt], 0, 0, 0);
                acc[mt][nt] = __builtin_amdgcn_mfma_f32_16x16x32_bf16(
                    ahi[mt], blo, acc[mt][nt], 0, 0, 0);
                acc[mt][nt] = __builtin_amdgcn_mfma_f32_16x16x32_bf16(
                    ahi[mt], bhi, acc[mt][nt], 0, 0, 0);
            }
        }
    }
    // Epilogue: C/D frag col=lane&15, row=(lane>>4)*4+i; shfl_xor(1) pairs cols.
    uint* __restrict__ O = (wave < 2) ? Olb : Orb;
    const int cbase = (wave * 64) & 127;
    const int crow0 = (lane >> 4) * 4;
    const bool evn = (lane & 1) == 0;
#pragma unroll
    for (int mt = 0; mt < 4; ++mt) {
#pragma unroll
        for (int i = 0; i < 4; ++i) {
            const int row = m0 + mt * 16 + crow0 + i;
#pragma unroll
            for (int nt = 0; nt < 4; ++nt) {
                float val = acc[mt][nt][i];
                float pv = __shfl_xor(val, 1);
                uint pk = (uint)bf16_rne(val) | ((uint)bf16_rne(pv) << 16);
                if (evn && row < nrows) {
                    const int col = cbase + nt * 16 + lrow;
                    O[(size_t)row * 64 + (col >> 1)] = pk;
                }
            }
        }
    }
}

// ---------------------------------------------------------------------------
// Fused GATv2 agg + bias + ELU + residual + LayerNorm. One wave per node.
// Wave-uniform CSR indices forced to SGPRs (readfirstlane) -> colv via scalar
// pipe, gathers in saddr form; pairwise math as f32x2 (v_pk_* ops).
// ---------------------------------------------------------------------------
template <bool RBF16, bool OBF16>
__global__ __launch_bounds__(256) void gat_agg(
    const uint* __restrict__ xl, const uint* __restrict__ xr,
    const int* __restrict__ offs, const int* __restrict__ colv,
    const float* __restrict__ att,
    const float* __restrict__ bias, const float* __restrict__ gamma,
    const float* __restrict__ beta, const void* __restrict__ resid,
    void* __restrict__ out, int nnode) {
    const int lane = threadIdx.x & 63;
    const int wid = __builtin_amdgcn_readfirstlane(threadIdx.x >> 6);
    const int wave0 = blockIdx.x * 4 + wid;
    const int wstride = gridDim.x * 4;
    const f32x2 att2 = ((const f32x2*)att)[lane];
    const f32x2 b2 = ((const f32x2*)bias)[lane];
    const f32x2 g2 = ((const f32x2*)gamma)[lane];
    const f32x2 be2 = ((const f32x2*)beta)[lane];
    for (int gid = wave0; gid < nnode; gid += wstride) {
        const uint xru = __builtin_nontemporal_load(xr + (size_t)gid * 64 + lane);
        const f32x2 xr2 = unpk(xru);
        float den = 0.f;
        f32x2 acc = {0.f, 0.f};
        int e = offs[gid];
        const int e1 = offs[gid + 1];
        for (; e + 4 <= e1; e += 4) {
            int s0 = __builtin_amdgcn_readfirstlane(colv[e]);
            int s1 = __builtin_amdgcn_readfirstlane(colv[e + 1]);
            int s2 = __builtin_amdgcn_readfirstlane(colv[e + 2]);
            int s3 = __builtin_amdgcn_readfirstlane(colv[e + 3]);
            uint u0 = xl[(size_t)s0 * 64 + lane];
            uint u1 = xl[(size_t)s1 * 64 + lane];
            uint u2 = xl[(size_t)s2 * 64 + lane];
            uint u3 = xl[(size_t)s3 * 64 + lane];
            f32x2 a0 = unpk(u0), a1 = unpk(u1), a2 = unpk(u2), a3 = unpk(u3);
            f32x2 m0 = a0 + xr2, m1 = a1 + xr2, m2 = a2 + xr2, m3 = a3 + xr2;
            f32x2 l0 = m0 * LEAKY, l1 = m1 * LEAKY, l2 = m2 * LEAKY, l3 = m3 * LEAKY;
            m0.x = fmaxf(m0.x, l0.x); m0.y = fmaxf(m0.y, l0.y);
            m1.x = fmaxf(m1.x, l1.x); m1.y = fmaxf(m1.y, l1.y);
            m2.x = fmaxf(m2.x, l2.x); m2.y = fmaxf(m2.y, l2.y);
            m3.x = fmaxf(m3.x, l3.x); m3.y = fmaxf(m3.y, l3.y);
            f32x2 t0 = m0 * att2, t1 = m1 * att2, t2 = m2 * att2, t3 = m3 * att2;
            float p0 = t0.x + t0.y, p1 = t1.x + t1.y;
            float p2 = t2.x + t2.y, p3 = t3.x + t3.y;
            p0 += __shfl_xor(p0, 1); p0 += __shfl_xor(p0, 2); p0 += __shfl_xor(p0, 4);
            p1 += __shfl_xor(p1, 1); p1 += __shfl_xor(p1, 2); p1 += __shfl_xor(p1, 4);
            p2 += __shfl_xor(p2, 1); p2 += __shfl_xor(p2, 2); p2 += __shfl_xor(p2, 4);
            p3 += __shfl_xor(p3, 1); p3 += __shfl_xor(p3, 2); p3 += __shfl_xor(p3, 4);
            float ex0 = __expf(p0), ex1 = __expf(p1);
            float ex2 = __expf(p2), ex3 = __expf(p3);
            den += (ex0 + ex1) + (ex2 + ex3);
            acc += a0 * ex0;
            acc += a1 * ex1;
            acc += a2 * ex2;
            acc += a3 * ex3;
        }
        for (; e < e1; ++e) {
            int s0 = __builtin_amdgcn_readfirstlane(colv[e]);
            uint u0 = xl[(size_t)s0 * 64 + lane];
            f32x2 a0 = unpk(u0);
            f32x2 m0 = a0 + xr2;
            f32x2 l0 = m0 * LEAKY;
            m0.x = fmaxf(m0.x, l0.x); m0.y = fmaxf(m0.y, l0.y);
            f32x2 t0 = m0 * att2;
            float p0 = t0.x + t0.y;
            p0 += __shfl_xor(p0, 1); p0 += __shfl_xor(p0, 2); p0 += __shfl_xor(p0, 4);
            float ex0 = __expf(p0);
            den += ex0;
            acc += a0 * ex0;
        }
        const float inv_den = 1.f / den;
        f32x2 v = acc * inv_den + b2;
        v.x = v.x > 0.f ? v.x : expm1f(v.x);     // ELU (alpha=1)
        v.y = v.y > 0.f ? v.y : expm1f(v.y);
        f32x2 r2;
        if (RBF16) {
            uint ru = __builtin_nontemporal_load(
                (const uint*)resid + (size_t)gid * 64 + lane);
            r2 = unpk(ru);
        } else {
            r2 = __builtin_nontemporal_load(
                (const f32x2*)resid + (size_t)gid * 64 + lane);
        }
        f32x2 tv = v + r2;
        float s = tv.x + tv.y, ss = tv.x * tv.x + tv.y * tv.y;
#pragma unroll
        for (int m = 1; m < 64; m <<= 1) {
            s += __shfl_xor(s, m);
            ss += __shfl_xor(ss, m);
        }
        const float mu = s * 0.0078125f;
        const float var = ss * 0.0078125f - mu * mu;
        const float iv = rsqrtf(var + LN_EPS);
        f32x2 o = (tv - mu) * iv * g2 + be2;
        if (OBF16) {
            uint po = (uint)bf16_rne(o.x) | ((uint)bf16_rne(o.y) << 16);
            __builtin_nontemporal_store(po, (uint*)out + (size_t)gid * 64 + lane);
        } else {
            __builtin_nontemporal_store(o, (f32x2*)out + (size_t)gid * 64 + lane);
        }
    }
}

// ---------------------------------------------------------------------------
extern "C" void kernel_launch(void* const* d_in, const int* in_sizes, int n_in,
                              void* d_out, int out_size, void* d_ws, size_t ws_size,
                              hipStream_t stream) {
    const float* x   = (const float*)d_in[0];
    const int*   ei  = (const int*)d_in[1];
    const float* Wl0 = (const float*)d_in[2];
    const float* Wr0 = (const float*)d_in[3];
    const float* at0 = (const float*)d_in[4];
    const float* b0  = (const float*)d_in[5];
    const float* g0  = (const float*)d_in[6];
    const float* be0 = (const float*)d_in[7];
    const float* Wl1 = (const float*)d_in[8];
    const float* Wr1 = (const float*)d_in[9];
    const float* at1 = (const float*)d_in[10];
    const float* b1  = (const float*)d_in[11];
    const float* g1  = (const float*)d_in[12];
    const float* be1 = (const float*)d_in[13];

    const int NF = in_sizes[0];        // N*128
    const int n  = NF / 128;           // nodes
    const int er = in_sizes[1] / 2;    // raw edges
    const int etot = er + n;           // + self-loops
    const int nb = (n + 1023) / 1024;  // scan blocks

    uint* A     = (uint*)d_ws;         // xl bf16-packed (N*64 uints)
    uint* B     = A + (size_t)NF / 2;  // xr bf16-packed
    uint* C1    = B + (size_t)NF / 2;  // layer-1 output, bf16-packed
    ushort* Whi = (ushort*)(C1 + (size_t)NF / 2);  // [2][32768] bf16 hi
    ushort* Wlo = Whi + 65536;                     // [2][32768] bf16 lo
    int* deg    = (int*)(Wlo + 65536);
    int* woff   = deg + n;
    int* offs   = woff + n;
    int* escan  = offs + (n + 4);      // n+1 used; +4 keeps colv 16B-aligned
    int* bsum   = escan + n;
    int* bpre   = bsum + 1024;
    int* colv   = bpre + 1024;
    float* C    = (float*)d_out;       // final fp32 output

    // ---- CSR build (XCD-partitioned) + both W conversions ----
    (void)hipMemsetAsync(deg, 0, (size_t)n * sizeof(int), stream);
    hist_part<<<2048, 256, 0, stream>>>(ei, er, etot, n, deg);
    scanA<<<nb, 1024, 0, stream>>>(deg, escan, bsum, n);
    scanB<<<1, 1024, 0, stream>>>(bsum, bpre, nb, offs, n);
    scanC<<<(n + 255) / 256, 256, 0, stream>>>(escan, bpre, offs, woff, n);
    fill_part<<<2048, 256, 0, stream>>>(ei, er, etot, n, woff, colv);
    cvt_w2<<<256, 256, 0, stream>>>(Wl0, Wr0, Wl1, Wr1, Whi, Wlo);

    const int gblk = (n + 63) / 64;

    // ---- layer 1: fp32 x -> A,B ; agg -> C1 (bf16 packed), resid = x fp32 ----
    gemm_mfma<false><<<gblk, 256, 0, stream>>>(x, Whi, Wlo, A, B, n);
    gat_agg<false, true><<<2048, 256, 0, stream>>>(
        A, B, offs, colv, at0, b0, g0, be0, x, C1, n);
    // ---- layer 2: bf16 C1 -> A,B ; agg -> d_out fp32, resid = C1 bf16 ----
    gemm_mfma<true><<<gblk, 256, 0, stream>>>(C1, Whi + 32768, Wlo + 32768,
                                              A, B, n);
    gat_agg<true, false><<<2048, 256, 0, stream>>>(
        A, B, offs, colv, at1, b1, g1, be1, C1, C, n);
}